// Round 4
// baseline (514.242 us; speedup 1.0000x reference)
//
#include <hip/hip_runtime.h>
#include <hip/hip_bf16.h>

#define B_ 4
#define C_ 512
#define L_ 2048
#define H_ 8
#define E_ 64
// sqrt(0.125 * log2(e)) — folded into Q (and K=Q) so QK^T yields log2-domain scores
#define QSCALE 0.4246609f
#define NUNITS 2048

typedef __attribute__((ext_vector_type(8))) short bf16x8;
typedef __attribute__((ext_vector_type(4))) float f32x4;

static __device__ __forceinline__ unsigned short f2bf(float f) {
    union { float f; unsigned u; } v; v.f = f;
    unsigned r = v.u + 0x7FFFu + ((v.u >> 16) & 1u);
    return (unsigned short)(r >> 16);
}

// ---------------- Pass A: cast x -> xb (bf16, [b][c][l]) and xt (bf16, [b][l][c]) ----------------
__global__ __launch_bounds__(256) void prep_kernel(const float* __restrict__ x,
                                                   unsigned short* __restrict__ xb,
                                                   unsigned short* __restrict__ xt) {
    const int lt = blockIdx.x, ct = blockIdx.y, b = blockIdx.z;
    const int l0 = lt * 64, c0 = ct * 64;
    const int t = threadIdx.x;
    __shared__ unsigned short T[64 * 72];

    const int cl = t >> 2, lo = (t & 3) * 16;
    const float* src = x + ((size_t)(b * C_ + c0 + cl)) * L_ + l0 + lo;
    unsigned short u[16];
    #pragma unroll
    for (int j = 0; j < 16; j += 4) {
        float4 v = *reinterpret_cast<const float4*>(src + j);
        u[j] = f2bf(v.x); u[j + 1] = f2bf(v.y); u[j + 2] = f2bf(v.z); u[j + 3] = f2bf(v.w);
    }
    unsigned short* xbp = xb + ((size_t)(b * C_ + c0 + cl)) * L_ + l0 + lo;
    reinterpret_cast<uint4*>(xbp)[0] = reinterpret_cast<uint4*>(u)[0];
    reinterpret_cast<uint4*>(xbp)[1] = reinterpret_cast<uint4*>(u)[1];
    reinterpret_cast<uint4*>(&T[cl * 72 + lo])[0] = reinterpret_cast<uint4*>(u)[0];
    reinterpret_cast<uint4*>(&T[cl * 72 + lo + 8])[0] = reinterpret_cast<uint4*>(u)[1];
    __syncthreads();
    const int ll = t >> 2, co = (t & 3) * 16;
    unsigned short v16[16];
    #pragma unroll
    for (int j = 0; j < 16; ++j) v16[j] = T[(co + j) * 72 + ll];
    unsigned short* xtp = xt + ((size_t)b * L_ + l0 + ll) * C_ + c0 + co;
    reinterpret_cast<uint4*>(xtp)[0] = reinterpret_cast<uint4*>(v16)[0];
    reinterpret_cast<uint4*>(xtp)[1] = reinterpret_cast<uint4*>(v16)[1];
}

// ---------------- Pass A2: cast W fp32 -> bf16 ----------------
__global__ __launch_bounds__(256) void wcast_kernel(const float* __restrict__ W,
                                                    unsigned short* __restrict__ Wb) {
    const int i = blockIdx.x * 256 + threadIdx.x;
    float4 v = reinterpret_cast<const float4*>(W)[i];
    union { unsigned short u[4]; unsigned long long ll; } o;
    o.u[0] = f2bf(v.x); o.u[1] = f2bf(v.y); o.u[2] = f2bf(v.z); o.u[3] = f2bf(v.w);
    reinterpret_cast<unsigned long long*>(Wb)[i] = o.ll;
}

// ---------------- Pass B: Q = (W x + b) * QSCALE, bf16 [(b*H+h)][l][e] ----------------
__global__ __launch_bounds__(256) void proj_kernel(const unsigned short* __restrict__ Wb,
                                                   const float* __restrict__ bq,
                                                   const unsigned short* __restrict__ xt,
                                                   unsigned short* __restrict__ qb) {
    const int lt = blockIdx.x, h = blockIdx.y, b = blockIdx.z;
    const int tid = threadIdx.x, w = tid >> 6, lane = tid & 63;
    const int lr = lane & 15, lg = lane >> 4;
    const int l = lt * 64 + w * 16 + lr;
    const int o0 = h * 64;

    f32x4 acc[4] = {};
    const unsigned short* xrow = xt + ((size_t)b * L_ + l) * C_;
    for (int ks = 0; ks < 16; ++ks) {
        bf16x8 bf = *reinterpret_cast<const bf16x8*>(xrow + ks * 32 + lg * 8);
        #pragma unroll
        for (int mt = 0; mt < 4; ++mt) {
            bf16x8 af = *reinterpret_cast<const bf16x8*>(Wb + (size_t)(o0 + mt * 16 + lr) * C_ + ks * 32 + lg * 8);
            acc[mt] = __builtin_amdgcn_mfma_f32_16x16x32_bf16(af, bf, acc[mt], 0, 0, 0);
        }
    }
    const int bh = b * H_ + h;
    unsigned short* qrow = qb + ((size_t)bh * L_ + l) * 64;
    #pragma unroll
    for (int mt = 0; mt < 4; ++mt) {
        const int e0 = mt * 16 + lg * 4;
        const float4 bb = *reinterpret_cast<const float4*>(bq + o0 + e0);
        union { unsigned short u[4]; unsigned long long ll; } o;
        o.u[0] = f2bf((acc[mt][0] + bb.x) * QSCALE);
        o.u[1] = f2bf((acc[mt][1] + bb.y) * QSCALE);
        o.u[2] = f2bf((acc[mt][2] + bb.z) * QSCALE);
        o.u[3] = f2bf((acc[mt][3] + bb.w) * QSCALE);
        *reinterpret_cast<unsigned long long*>(qrow + e0) = o.ll;
    }
}

// ---------------- Pass C: fused S/softmax-sum/PV + residual + transposed write ----------------
// One PV phase: consume V bank CUR, prefetch into bank NXT (next ks, or next k-tile's ks=0)
#define PV_PHASE(CUR, NXT, KS)                                                      \
    {                                                                               \
        const bool pf = ((KS) + 1 < ksmax) || (kt + 1 < nkt);                       \
        const int nl = ((KS) + 1 < ksmax) ? k0 + ((KS) + 1) * 32 : k0 + 128;        \
        if (pf) {                                                                   \
            _Pragma("unroll")                                                       \
            for (int ct = 0; ct < 2; ++ct)                                          \
                pvv[NXT][ct] = *reinterpret_cast<const bf16x8*>(                    \
                    Vbase + (size_t)(c0w + ct * 16 + lr) * L_ + nl + lg * 8);       \
        }                                                                           \
        bf16x8 pa[4];                                                               \
        _Pragma("unroll")                                                           \
        for (int mt = 0; mt < 4; ++mt) {                                            \
            const int row = mt * 16 + lr;                                           \
            const int g2 = ((KS) * 4 + lg) ^ lr;                                    \
            pa[mt] = *reinterpret_cast<const bf16x8*>(&Pb[row * 128 + (g2 << 3)]);  \
        }                                                                           \
        __builtin_amdgcn_s_setprio(1);                                              \
        _Pragma("unroll")                                                           \
        for (int mt = 0; mt < 4; ++mt)                                              \
            _Pragma("unroll")                                                       \
            for (int ct = 0; ct < 2; ++ct)                                          \
                acc[mt][ct] = __builtin_amdgcn_mfma_f32_16x16x32_bf16(              \
                    pa[mt], pvv[CUR][ct], acc[mt][ct], 0, 0, 0);                    \
        __builtin_amdgcn_s_setprio(0);                                              \
    }

__global__ __launch_bounds__(512, 6) void pv_kernel(const unsigned short* __restrict__ qb,
                                                    const unsigned short* __restrict__ xb,
                                                    float* __restrict__ out,
                                                    int* __restrict__ counter) {
    const int tid = threadIdx.x, w = tid >> 6, lane = tid & 63;
    const int lr = lane & 15, lg = lane >> 4;

    __shared__ unsigned short Qt[64 * 64];       // swizzled Q tile
    __shared__ unsigned short P2[2][64 * 128];   // double-buffered P, XOR-swizzled
    __shared__ float rsT[64][8];                 // per-wave rowsum partials
    __shared__ int s_u;

    for (;;) {
        __syncthreads();   // previous unit's readers of Qt/P2/rsT/s_u are done
        if (tid == 0) s_u = atomicAdd(counter, 1);
        __syncthreads();
        const int u = s_u;
        if (u >= NUNITS) return;

        // heavy q-tiles first (LPT packing on the dynamic queue)
        const int qt = 31 - (u >> 6);
        const int rr = u & 63;
        const int b = rr >> 4, h = (rr >> 1) & 7, chalf = rr & 1;
        const int q0 = qt * 64, qlim = q0 + 63;
        const int nkt = (q0 >> 7) + 1;
        const int bh = b * H_ + h;
        const int c0w = chalf * 256 + w * 32;    // this wave's 32-channel slice
        const unsigned short* Qbase = qb + (size_t)bh * L_ * 64;
        const unsigned short* Vbase = xb + (size_t)b * C_ * L_;

        // stage Q tile into LDS (granule g -> g ^ (row&7))
        {
            const int r = tid >> 3, g = tid & 7;
            bf16x8 v = *reinterpret_cast<const bf16x8*>(Qbase + (size_t)(q0 + r) * 64 + g * 8);
            *reinterpret_cast<bf16x8*>(&Qt[r * 64 + ((g ^ (r & 7)) << 3)]) = v;
        }
        // preload K slab for k-tile 0
        bf16x8 kb0 = *reinterpret_cast<const bf16x8*>(Qbase + (size_t)(w * 16 + lr) * 64 + lg * 8);
        bf16x8 kb1 = *reinterpret_cast<const bf16x8*>(Qbase + (size_t)(w * 16 + lr) * 64 + 32 + lg * 8);
        // preload V bank A for (kt=0, ks=0)
        bf16x8 pvv[2][2];
        #pragma unroll
        for (int ct = 0; ct < 2; ++ct)
            pvv[0][ct] = *reinterpret_cast<const bf16x8*>(Vbase + (size_t)(c0w + ct * 16 + lr) * L_ + lg * 8);

        f32x4 acc[4][2] = {};
        float rs[4] = {0.f, 0.f, 0.f, 0.f};

        __syncthreads();   // Qt visible

        #pragma unroll 1
        for (int kt = 0; kt < nkt; ++kt) {
            const int k0 = kt * 128;
            const int ksmax = min(4, ((qlim - k0) >> 5) + 1);   // 2 or 4
            unsigned short* Pb = (unsigned short*)P2[kt & 1];
            const bool active = (k0 + (w & ~1) * 16) <= qlim;

            if (active) {
                // S phase: z = K-slab x Q -> D[k][q], 4 consecutive k per lane
                f32x4 z[4];
                #pragma unroll
                for (int nt = 0; nt < 4; ++nt) {
                    bf16x8 aq0 = *reinterpret_cast<const bf16x8*>(&Qt[(nt * 16 + lr) * 64 + ((lg ^ (lr & 7)) << 3)]);
                    bf16x8 aq1 = *reinterpret_cast<const bf16x8*>(&Qt[(nt * 16 + lr) * 64 + (((4 + lg) ^ (lr & 7)) << 3)]);
                    f32x4 zz = {};
                    zz = __builtin_amdgcn_mfma_f32_16x16x32_bf16(kb0, aq0, zz, 0, 0, 0);
                    zz = __builtin_amdgcn_mfma_f32_16x16x32_bf16(kb1, aq1, zz, 0, 0, 0);
                    z[nt] = zz;
                }
                if (kt + 1 < nkt) {   // prefetch next K slab under the exp tail
                    const size_t krow = (size_t)(k0 + 128 + w * 16 + lr) * 64;
                    kb0 = *reinterpret_cast<const bf16x8*>(Qbase + krow + lg * 8);
                    kb1 = *reinterpret_cast<const bf16x8*>(Qbase + krow + 32 + lg * 8);
                }
                const int kbase = k0 + w * 16 + lg * 4;
                #pragma unroll
                for (int nt = 0; nt < 4; ++nt) {
                    const int q = q0 + nt * 16 + lr;
                    const float p0 = (kbase + 0 <= q) ? exp2f(z[nt][0]) : 0.f;
                    const float p1 = (kbase + 1 <= q) ? exp2f(z[nt][1]) : 0.f;
                    const float p2 = (kbase + 2 <= q) ? exp2f(z[nt][2]) : 0.f;
                    const float p3 = (kbase + 3 <= q) ? exp2f(z[nt][3]) : 0.f;
                    rs[nt] += (p0 + p1) + (p2 + p3);
                    unsigned r01, r23;
                    asm("v_cvt_pk_bf16_f32 %0, %1, %2" : "=v"(r01) : "v"(p0), "v"(p1));
                    asm("v_cvt_pk_bf16_f32 %0, %1, %2" : "=v"(r23) : "v"(p2), "v"(p3));
                    const int row = nt * 16 + lr;
                    const int col = w * 16 + lg * 4;
                    const int gg = (col >> 3) ^ lr;
                    const unsigned long long pk = ((unsigned long long)r23 << 32) | r01;
                    *reinterpret_cast<unsigned long long*>(&Pb[row * 128 + (gg << 3) + (col & 7)]) = pk;
                }
            } else if (kt + 1 < nkt) {
                const size_t krow = (size_t)(k0 + 128 + w * 16 + lr) * 64;
                kb0 = *reinterpret_cast<const bf16x8*>(Qbase + krow + lg * 8);
                kb1 = *reinterpret_cast<const bf16x8*>(Qbase + krow + 32 + lg * 8);
            }
            __syncthreads();   // P ready

            // PV: wave owns 32 channels; 2-bank register pipeline on V
            PV_PHASE(0, 1, 0)
            PV_PHASE(1, 0, 1)
            if (ksmax == 4) {
                PV_PHASE(0, 1, 2)
                PV_PHASE(1, 0, 3)
            }
        }

        // rowsum: reduce across lg groups, then across waves via LDS
        #pragma unroll
        for (int nt = 0; nt < 4; ++nt) {
            float t0 = __shfl_xor(rs[nt], 16); rs[nt] += t0;
            float t1 = __shfl_xor(rs[nt], 32); rs[nt] += t1;
        }
        if (lg == 0) {
            #pragma unroll
            for (int nt = 0; nt < 4; ++nt) rsT[nt * 16 + lr][w] = rs[nt];
        }
        __syncthreads();
        float li[16];
        #pragma unroll
        for (int mt = 0; mt < 4; ++mt)
            #pragma unroll
            for (int r = 0; r < 4; ++r) {
                const int row = mt * 16 + lg * 4 + r;
                const f32x4 s0 = *reinterpret_cast<const f32x4*>(&rsT[row][0]);
                const f32x4 s1 = *reinterpret_cast<const f32x4*>(&rsT[row][4]);
                li[mt * 4 + r] = 1.f / (((s0[0] + s0[1]) + (s0[2] + s0[3])) + ((s1[0] + s1[1]) + (s1[2] + s1[3])));
            }

        // epilogue: bf16 residual from xb; ct-outer/mt-inner for write merging
        const unsigned short* xres = xb + (size_t)b * C_ * L_;
        float* ob = out + (size_t)bh * C_ * L_;
        #pragma unroll
        for (int ct = 0; ct < 2; ++ct) {
            const int c = c0w + ct * 16 + lr;
            #pragma unroll
            for (int mt = 0; mt < 4; ++mt) {
                const int lbase = q0 + mt * 16 + lg * 4;
                const ushort4 rv = *reinterpret_cast<const ushort4*>(xres + (size_t)c * L_ + lbase);
                f32x4 o;
                o[0] = acc[mt][ct][0] * li[mt * 4 + 0] + __uint_as_float((unsigned)rv.x << 16);
                o[1] = acc[mt][ct][1] * li[mt * 4 + 1] + __uint_as_float((unsigned)rv.y << 16);
                o[2] = acc[mt][ct][2] * li[mt * 4 + 2] + __uint_as_float((unsigned)rv.z << 16);
                o[3] = acc[mt][ct][3] * li[mt * 4 + 3] + __uint_as_float((unsigned)rv.w << 16);
                *reinterpret_cast<f32x4*>(ob + (size_t)c * L_ + lbase) = o;
            }
        }
    }
}

extern "C" void kernel_launch(void* const* d_in, const int* in_sizes, int n_in,
                              void* d_out, int out_size, void* d_ws, size_t ws_size,
                              hipStream_t stream) {
    const float* x  = (const float*)d_in[0];
    const float* Wq = (const float*)d_in[1];
    const float* bq = (const float*)d_in[2];
    float* out = (float*)d_out;

    unsigned short* xb   = (unsigned short*)d_ws;                        // B*C*L bf16   = 8 MiB
    unsigned short* xt   = xb + (size_t)B_ * C_ * L_;                    // B*L*C bf16   = 8 MiB
    unsigned short* qbuf = xt + (size_t)B_ * L_ * C_;                    // B*H*L*E bf16 = 8 MiB
    unsigned short* Wb   = qbuf + (size_t)B_ * H_ * L_ * E_;             // 512 KiB
    int* counter = (int*)(Wb + (size_t)H_ * E_ * C_);                    // 4 B

    hipMemsetAsync(counter, 0, 4, stream);
    prep_kernel<<<dim3(32, 8, 4), 256, 0, stream>>>(x, xb, xt);
    wcast_kernel<<<dim3(256), 256, 0, stream>>>(Wq, Wb);
    proj_kernel<<<dim3(32, 8, 4), 256, 0, stream>>>(Wb, bq, xt, qbuf);
    pv_kernel<<<dim3(768), 512, 0, stream>>>(qbuf, xb, out, counter);
}

// Round 5
// 285.380 us; speedup vs baseline: 1.8020x; 1.8020x over previous
//
#include <hip/hip_runtime.h>
#include <hip/hip_bf16.h>

#define B_ 4
#define C_ 512
#define L_ 2048
#define H_ 8
#define E_ 64
// sqrt(0.125 * log2(e)) — folded into Q (and K=Q) so QK^T yields log2-domain scores
#define QSCALE 0.4246609f
#define NUNITS 1024

typedef __attribute__((ext_vector_type(8))) short bf16x8;
typedef __attribute__((ext_vector_type(4))) float f32x4;

static __device__ __forceinline__ unsigned short f2bf(float f) {
    union { float f; unsigned u; } v; v.f = f;
    unsigned r = v.u + 0x7FFFu + ((v.u >> 16) & 1u);
    return (unsigned short)(r >> 16);
}

// light barrier: make LDS writes visible, do NOT drain vmcnt (loads stay in flight)
#define LBAR() do { asm volatile("s_waitcnt lgkmcnt(0)" ::: "memory"); \
                    __builtin_amdgcn_s_barrier(); } while (0)

// ---------------- Pass A: cast x -> xb (bf16, [b][c][l]) and xt (bf16, [b][l][c]) ----------------
__global__ __launch_bounds__(256) void prep_kernel(const float* __restrict__ x,
                                                   unsigned short* __restrict__ xb,
                                                   unsigned short* __restrict__ xt) {
    const int lt = blockIdx.x, ct = blockIdx.y, b = blockIdx.z;
    const int l0 = lt * 64, c0 = ct * 64;
    const int t = threadIdx.x;
    __shared__ unsigned short T[64 * 72];

    const int cl = t >> 2, lo = (t & 3) * 16;
    const float* src = x + ((size_t)(b * C_ + c0 + cl)) * L_ + l0 + lo;
    unsigned short u[16];
    #pragma unroll
    for (int j = 0; j < 16; j += 4) {
        float4 v = *reinterpret_cast<const float4*>(src + j);
        u[j] = f2bf(v.x); u[j + 1] = f2bf(v.y); u[j + 2] = f2bf(v.z); u[j + 3] = f2bf(v.w);
    }
    unsigned short* xbp = xb + ((size_t)(b * C_ + c0 + cl)) * L_ + l0 + lo;
    reinterpret_cast<uint4*>(xbp)[0] = reinterpret_cast<uint4*>(u)[0];
    reinterpret_cast<uint4*>(xbp)[1] = reinterpret_cast<uint4*>(u)[1];
    reinterpret_cast<uint4*>(&T[cl * 72 + lo])[0] = reinterpret_cast<uint4*>(u)[0];
    reinterpret_cast<uint4*>(&T[cl * 72 + lo + 8])[0] = reinterpret_cast<uint4*>(u)[1];
    __syncthreads();
    const int ll = t >> 2, co = (t & 3) * 16;
    unsigned short v16[16];
    #pragma unroll
    for (int j = 0; j < 16; ++j) v16[j] = T[(co + j) * 72 + ll];
    unsigned short* xtp = xt + ((size_t)b * L_ + l0 + ll) * C_ + c0 + co;
    reinterpret_cast<uint4*>(xtp)[0] = reinterpret_cast<uint4*>(v16)[0];
    reinterpret_cast<uint4*>(xtp)[1] = reinterpret_cast<uint4*>(v16)[1];
}

// ---------------- Pass A2: cast W fp32 -> bf16 ----------------
__global__ __launch_bounds__(256) void wcast_kernel(const float* __restrict__ W,
                                                    unsigned short* __restrict__ Wb) {
    const int i = blockIdx.x * 256 + threadIdx.x;
    float4 v = reinterpret_cast<const float4*>(W)[i];
    union { unsigned short u[4]; unsigned long long ll; } o;
    o.u[0] = f2bf(v.x); o.u[1] = f2bf(v.y); o.u[2] = f2bf(v.z); o.u[3] = f2bf(v.w);
    reinterpret_cast<unsigned long long*>(Wb)[i] = o.ll;
}

// ---------------- Pass B: Q = (W x + b) * QSCALE, bf16 [(b*H+h)][l][e] ----------------
__global__ __launch_bounds__(256) void proj_kernel(const unsigned short* __restrict__ Wb,
                                                   const float* __restrict__ bq,
                                                   const unsigned short* __restrict__ xt,
                                                   unsigned short* __restrict__ qb) {
    const int lt = blockIdx.x, h = blockIdx.y, b = blockIdx.z;
    const int tid = threadIdx.x, w = tid >> 6, lane = tid & 63;
    const int lr = lane & 15, lg = lane >> 4;
    const int l = lt * 64 + w * 16 + lr;
    const int o0 = h * 64;

    f32x4 acc[4] = {};
    const unsigned short* xrow = xt + ((size_t)b * L_ + l) * C_;
    for (int ks = 0; ks < 16; ++ks) {
        bf16x8 bf = *reinterpret_cast<const bf16x8*>(xrow + ks * 32 + lg * 8);
        #pragma unroll
        for (int mt = 0; mt < 4; ++mt) {
            bf16x8 af = *reinterpret_cast<const bf16x8*>(Wb + (size_t)(o0 + mt * 16 + lr) * C_ + ks * 32 + lg * 8);
            acc[mt] = __builtin_amdgcn_mfma_f32_16x16x32_bf16(af, bf, acc[mt], 0, 0, 0);
        }
    }
    const int bh = b * H_ + h;
    unsigned short* qrow = qb + ((size_t)bh * L_ + l) * 64;
    #pragma unroll
    for (int mt = 0; mt < 4; ++mt) {
        const int e0 = mt * 16 + lg * 4;
        const float4 bb = *reinterpret_cast<const float4*>(bq + o0 + e0);
        union { unsigned short u[4]; unsigned long long ll; } o;
        o.u[0] = f2bf((acc[mt][0] + bb.x) * QSCALE);
        o.u[1] = f2bf((acc[mt][1] + bb.y) * QSCALE);
        o.u[2] = f2bf((acc[mt][2] + bb.z) * QSCALE);
        o.u[3] = f2bf((acc[mt][3] + bb.w) * QSCALE);
        *reinterpret_cast<unsigned long long*>(qrow + e0) = o.ll;
    }
}

// ---------------- Pass C: fused S/softmax-sum/PV + residual + transposed write ----------------
// One PV phase: consume V bank CUR, prefetch into bank NXT (next ks, or next k-tile's ks=0)
#define PV_PHASE(CUR, NXT, KS)                                                      \
    {                                                                               \
        const bool pf = ((KS) + 1 < ksmax) || (kt + 1 < nkt);                       \
        const int nl = ((KS) + 1 < ksmax) ? k0 + ((KS) + 1) * 32 : k0 + 128;        \
        if (pf) {                                                                   \
            _Pragma("unroll")                                                       \
            for (int ct = 0; ct < 4; ++ct)                                          \
                pvv[NXT][ct] = *reinterpret_cast<const bf16x8*>(                    \
                    Vbase + (size_t)(c0w + ct * 16 + lr) * L_ + nl + lg * 8);       \
        }                                                                           \
        bf16x8 pa[4];                                                               \
        _Pragma("unroll")                                                           \
        for (int mt = 0; mt < 4; ++mt) {                                            \
            const int row = mt * 16 + lr;                                           \
            const int g2 = ((KS) * 4 + lg) ^ lr;                                    \
            pa[mt] = *reinterpret_cast<const bf16x8*>(&Pb[row * 128 + (g2 << 3)]);  \
        }                                                                           \
        __builtin_amdgcn_s_setprio(1);                                              \
        _Pragma("unroll")                                                           \
        for (int mt = 0; mt < 4; ++mt)                                              \
            _Pragma("unroll")                                                       \
            for (int ct = 0; ct < 4; ++ct)                                          \
                acc[mt][ct] = __builtin_amdgcn_mfma_f32_16x16x32_bf16(              \
                    pa[mt], pvv[CUR][ct], acc[mt][ct], 0, 0, 0);                    \
        __builtin_amdgcn_s_setprio(0);                                              \
    }

__global__ __launch_bounds__(512, 3) void pv_kernel(const unsigned short* __restrict__ qb,
                                                    const unsigned short* __restrict__ xb,
                                                    float* __restrict__ out,
                                                    int* __restrict__ counter) {
    const int tid = threadIdx.x, w = tid >> 6, lane = tid & 63;
    const int lr = lane & 15, lg = lane >> 4;
    const int c0w = w * 64;                      // this wave's 64-channel slice

    __shared__ unsigned short Qt[64 * 64];       // swizzled Q tile
    __shared__ unsigned short P2[2][64 * 128];   // double-buffered P, XOR-swizzled
    __shared__ float rsT[64][8];                 // per-wave rowsum partials
    __shared__ int s_u;

    for (;;) {
        __syncthreads();   // previous unit's readers of Qt/P2/rsT/s_u are done
        if (tid == 0) s_u = atomicAdd(counter, 1);
        __syncthreads();
        const int u = s_u;
        if (u >= NUNITS) return;

        // heavy q-tiles first (LPT packing on the dynamic queue)
        const int qt = 31 - (u >> 5);
        const int rr = u & 31;
        const int b = rr >> 3, h = rr & 7;
        const int q0 = qt * 64, qlim = q0 + 63;
        const int nkt = (q0 >> 7) + 1;
        const int bh = b * H_ + h;
        const unsigned short* Qbase = qb + (size_t)bh * L_ * 64;
        const unsigned short* Vbase = xb + (size_t)b * C_ * L_;

        // stage Q tile into LDS (granule g -> g ^ (row&7))
        {
            const int r = tid >> 3, g = tid & 7;
            bf16x8 v = *reinterpret_cast<const bf16x8*>(Qbase + (size_t)(q0 + r) * 64 + g * 8);
            *reinterpret_cast<bf16x8*>(&Qt[r * 64 + ((g ^ (r & 7)) << 3)]) = v;
        }
        // preload K slab for k-tile 0
        bf16x8 kb0 = *reinterpret_cast<const bf16x8*>(Qbase + (size_t)(w * 16 + lr) * 64 + lg * 8);
        bf16x8 kb1 = *reinterpret_cast<const bf16x8*>(Qbase + (size_t)(w * 16 + lr) * 64 + 32 + lg * 8);
        // preload V bank A for (kt=0, ks=0)
        bf16x8 pvv[2][4];
        #pragma unroll
        for (int ct = 0; ct < 4; ++ct)
            pvv[0][ct] = *reinterpret_cast<const bf16x8*>(Vbase + (size_t)(c0w + ct * 16 + lr) * L_ + lg * 8);

        f32x4 acc[4][4] = {};
        float rs[4] = {0.f, 0.f, 0.f, 0.f};

        LBAR();   // Qt visible; preloads stay in flight

        #pragma unroll 1
        for (int kt = 0; kt < nkt; ++kt) {
            const int k0 = kt * 128;
            const int ksmax = min(4, ((qlim - k0) >> 5) + 1);   // 2 or 4
            unsigned short* Pb = (unsigned short*)P2[kt & 1];
            const bool active = (k0 + (w & ~1) * 16) <= qlim;

            if (active) {
                // S phase: z = K-slab x Q -> D[k][q], 4 consecutive k per lane
                f32x4 z[4];
                #pragma unroll
                for (int nt = 0; nt < 4; ++nt) {
                    bf16x8 aq0 = *reinterpret_cast<const bf16x8*>(&Qt[(nt * 16 + lr) * 64 + ((lg ^ (lr & 7)) << 3)]);
                    bf16x8 aq1 = *reinterpret_cast<const bf16x8*>(&Qt[(nt * 16 + lr) * 64 + (((4 + lg) ^ (lr & 7)) << 3)]);
                    f32x4 zz = {};
                    zz = __builtin_amdgcn_mfma_f32_16x16x32_bf16(kb0, aq0, zz, 0, 0, 0);
                    zz = __builtin_amdgcn_mfma_f32_16x16x32_bf16(kb1, aq1, zz, 0, 0, 0);
                    z[nt] = zz;
                }
                if (kt + 1 < nkt) {   // prefetch next K slab under the exp tail
                    const size_t krow = (size_t)(k0 + 128 + w * 16 + lr) * 64;
                    kb0 = *reinterpret_cast<const bf16x8*>(Qbase + krow + lg * 8);
                    kb1 = *reinterpret_cast<const bf16x8*>(Qbase + krow + 32 + lg * 8);
                }
                const int kbase = k0 + w * 16 + lg * 4;
                #pragma unroll
                for (int nt = 0; nt < 4; ++nt) {
                    const int q = q0 + nt * 16 + lr;
                    const float p0 = (kbase + 0 <= q) ? exp2f(z[nt][0]) : 0.f;
                    const float p1 = (kbase + 1 <= q) ? exp2f(z[nt][1]) : 0.f;
                    const float p2 = (kbase + 2 <= q) ? exp2f(z[nt][2]) : 0.f;
                    const float p3 = (kbase + 3 <= q) ? exp2f(z[nt][3]) : 0.f;
                    rs[nt] += (p0 + p1) + (p2 + p3);
                    unsigned r01, r23;
                    asm("v_cvt_pk_bf16_f32 %0, %1, %2" : "=v"(r01) : "v"(p0), "v"(p1));
                    asm("v_cvt_pk_bf16_f32 %0, %1, %2" : "=v"(r23) : "v"(p2), "v"(p3));
                    const int row = nt * 16 + lr;
                    const int col = w * 16 + lg * 4;
                    const int gg = (col >> 3) ^ lr;
                    const unsigned long long pk = ((unsigned long long)r23 << 32) | r01;
                    *reinterpret_cast<unsigned long long*>(&Pb[row * 128 + (gg << 3) + (col & 7)]) = pk;
                }
            } else if (kt + 1 < nkt) {
                const size_t krow = (size_t)(k0 + 128 + w * 16 + lr) * 64;
                kb0 = *reinterpret_cast<const bf16x8*>(Qbase + krow + lg * 8);
                kb1 = *reinterpret_cast<const bf16x8*>(Qbase + krow + 32 + lg * 8);
            }
            LBAR();   // P visible; K/V prefetches stay in flight (counted vmcnt at use)

            // PV: wave owns 64 channels; 2-bank register pipeline on V
            PV_PHASE(0, 1, 0)
            PV_PHASE(1, 0, 1)
            if (ksmax == 4) {
                PV_PHASE(0, 1, 2)
                PV_PHASE(1, 0, 3)
            }
        }

        // rowsum: reduce across lg groups, then across waves via LDS
        #pragma unroll
        for (int nt = 0; nt < 4; ++nt) {
            float t0 = __shfl_xor(rs[nt], 16); rs[nt] += t0;
            float t1 = __shfl_xor(rs[nt], 32); rs[nt] += t1;
        }
        if (lg == 0) {
            #pragma unroll
            for (int nt = 0; nt < 4; ++nt) rsT[nt * 16 + lr][w] = rs[nt];
        }
        LBAR();
        float li[16];
        #pragma unroll
        for (int mt = 0; mt < 4; ++mt)
            #pragma unroll
            for (int r = 0; r < 4; ++r) {
                const int row = mt * 16 + lg * 4 + r;
                const f32x4 s0 = *reinterpret_cast<const f32x4*>(&rsT[row][0]);
                const f32x4 s1 = *reinterpret_cast<const f32x4*>(&rsT[row][4]);
                li[mt * 4 + r] = 1.f / (((s0[0] + s0[1]) + (s0[2] + s0[3])) + ((s1[0] + s1[1]) + (s1[2] + s1[3])));
            }

        // epilogue: bf16 residual from xb; ct-outer/mt-inner for write merging
        const unsigned short* xres = xb + (size_t)b * C_ * L_;
        float* ob = out + (size_t)bh * C_ * L_;
        #pragma unroll
        for (int ct = 0; ct < 4; ++ct) {
            const int c = c0w + ct * 16 + lr;
            #pragma unroll
            for (int mt = 0; mt < 4; ++mt) {
                const int lbase = q0 + mt * 16 + lg * 4;
                const ushort4 rv = *reinterpret_cast<const ushort4*>(xres + (size_t)c * L_ + lbase);
                f32x4 o;
                o[0] = acc[mt][ct][0] * li[mt * 4 + 0] + __uint_as_float((unsigned)rv.x << 16);
                o[1] = acc[mt][ct][1] * li[mt * 4 + 1] + __uint_as_float((unsigned)rv.y << 16);
                o[2] = acc[mt][ct][2] * li[mt * 4 + 2] + __uint_as_float((unsigned)rv.z << 16);
                o[3] = acc[mt][ct][3] * li[mt * 4 + 3] + __uint_as_float((unsigned)rv.w << 16);
                *reinterpret_cast<f32x4*>(ob + (size_t)c * L_ + lbase) = o;
            }
        }
    }
}

extern "C" void kernel_launch(void* const* d_in, const int* in_sizes, int n_in,
                              void* d_out, int out_size, void* d_ws, size_t ws_size,
                              hipStream_t stream) {
    const float* x  = (const float*)d_in[0];
    const float* Wq = (const float*)d_in[1];
    const float* bq = (const float*)d_in[2];
    float* out = (float*)d_out;

    unsigned short* xb   = (unsigned short*)d_ws;                        // B*C*L bf16   = 8 MiB
    unsigned short* xt   = xb + (size_t)B_ * C_ * L_;                    // B*L*C bf16   = 8 MiB
    unsigned short* qbuf = xt + (size_t)B_ * L_ * C_;                    // B*H*L*E bf16 = 8 MiB
    unsigned short* Wb   = qbuf + (size_t)B_ * H_ * L_ * E_;             // 512 KiB
    int* counter = (int*)(Wb + (size_t)H_ * E_ * C_);                    // 4 B

    hipMemsetAsync(counter, 0, 4, stream);
    prep_kernel<<<dim3(32, 8, 4), 256, 0, stream>>>(x, xb, xt);
    wcast_kernel<<<dim3(256), 256, 0, stream>>>(Wq, Wb);
    proj_kernel<<<dim3(32, 8, 4), 256, 0, stream>>>(Wb, bq, xt, qbuf);
    pv_kernel<<<dim3(768), 512, 0, stream>>>(qbuf, xb, out, counter);
}